// Round 1
// baseline (133.116 us; speedup 1.0000x reference)
//
#include <hip/hip_runtime.h>
#include <math.h>

#define NATOMS 3000
#define DIM 16
#define NRBF 16
#define CUTOFF 5.0f
#define BOX 45.0f
#define GAMMA 10.0f

// One block per atom i: aggregate messages over all j, then per-atom MLP tail.
__global__ __launch_bounds__(256) void gnn_atom_kernel(
    const float* __restrict__ xyz, const int* __restrict__ zsp,
    const float* __restrict__ embed, const float* __restrict__ W_rbf,
    const float* __restrict__ W_msg, const float* __restrict__ W1,
    const float* __restrict__ W2, float* __restrict__ e_out)
{
    __shared__ float wrbf[NRBF * DIM];
    __shared__ float red[4][DIM];
    __shared__ float mfin[DIM];
    __shared__ float hn[DIM];
    __shared__ float t1l[DIM];

    const int tid = threadIdx.x;
    const int i = blockIdx.x;

    if (tid < NRBF * DIM) wrbf[tid] = W_rbf[tid];
    __syncthreads();

    const float xi = xyz[3 * i + 0];
    const float yi = xyz[3 * i + 1];
    const float zi = xyz[3 * i + 2];

    float m[DIM];
#pragma unroll
    for (int d = 0; d < DIM; ++d) m[d] = 0.0f;

    for (int j = tid; j < NATOMS; j += 256) {
        float dx = xyz[3 * j + 0] - xi;
        float dy = xyz[3 * j + 1] - yi;
        float dz = xyz[3 * j + 2] - zi;
        // minimum-image wrap, matching reference comparisons exactly
        dx += ((dx < -0.5f * BOX) ? BOX : 0.0f) - ((dx >= 0.5f * BOX) ? BOX : 0.0f);
        dy += ((dy < -0.5f * BOX) ? BOX : 0.0f) - ((dy >= 0.5f * BOX) ? BOX : 0.0f);
        dz += ((dz < -0.5f * BOX) ? BOX : 0.0f) - ((dz >= 0.5f * BOX) ? BOX : 0.0f);
        float dsq = dx * dx + dy * dy + dz * dz;
        if (dsq > 0.0f && dsq < CUTOFF * CUTOFF) {
            float r = sqrtf(dsq);
            float rbf[NRBF];
#pragma unroll
            for (int k = 0; k < NRBF; ++k) {
                float t = r - (float)k * (CUTOFF / (float)(NRBF - 1));
                rbf[k] = __expf(-GAMMA * t * t);
            }
            const float* hj = embed + (size_t)zsp[j] * DIM;
#pragma unroll
            for (int d = 0; d < DIM; ++d) {
                float f = 0.0f;
#pragma unroll
                for (int k = 0; k < NRBF; ++k) f += rbf[k] * wrbf[k * DIM + d];
                m[d] += f * hj[d];
            }
        }
    }

    // wave-level reduction of m[16] across 64 lanes
#pragma unroll
    for (int d = 0; d < DIM; ++d) {
        float v = m[d];
        for (int off = 32; off >= 1; off >>= 1) v += __shfl_down(v, off, 64);
        m[d] = v;
    }
    const int wave = tid >> 6;
    const int lane = tid & 63;
    if (lane == 0) {
#pragma unroll
        for (int d = 0; d < DIM; ++d) red[wave][d] = m[d];
    }
    __syncthreads();

    if (tid < DIM) {
        mfin[tid] = red[0][tid] + red[1][tid] + red[2][tid] + red[3][tid];
    }
    __syncthreads();

    if (tid < DIM) {
        float acc = 0.0f;
#pragma unroll
        for (int d = 0; d < DIM; ++d) acc += mfin[d] * W_msg[d * DIM + tid];
        float hi = embed[(size_t)zsp[i] * DIM + tid];
        hn[tid] = hi + tanhf(acc);
    }
    __syncthreads();

    if (tid < DIM) {
        float acc = 0.0f;
#pragma unroll
        for (int d = 0; d < DIM; ++d) acc += hn[d] * W1[d * DIM + tid];
        t1l[tid] = tanhf(acc);
    }
    __syncthreads();

    if (tid == 0) {
        float e = 0.0f;
#pragma unroll
        for (int d = 0; d < DIM; ++d) e += t1l[d] * W2[d];
        e_out[i] = e;
    }
}

// Deterministic final reduction of per-atom energies -> scalar.
__global__ __launch_bounds__(256) void gnn_reduce_kernel(
    const float* __restrict__ e, float* __restrict__ out)
{
    __shared__ float red[4];
    const int tid = threadIdx.x;
    float s = 0.0f;
    for (int i = tid; i < NATOMS; i += 256) s += e[i];
    for (int off = 32; off >= 1; off >>= 1) s += __shfl_down(s, off, 64);
    const int wave = tid >> 6;
    const int lane = tid & 63;
    if (lane == 0) red[wave] = s;
    __syncthreads();
    if (tid == 0) out[0] = red[0] + red[1] + red[2] + red[3];
}

extern "C" void kernel_launch(void* const* d_in, const int* in_sizes, int n_in,
                              void* d_out, int out_size, void* d_ws, size_t ws_size,
                              hipStream_t stream) {
    const float* xyz   = (const float*)d_in[0];
    const int*   zsp   = (const int*)d_in[1];
    const float* embed = (const float*)d_in[2];
    const float* W_rbf = (const float*)d_in[3];
    const float* W_msg = (const float*)d_in[4];
    const float* W1    = (const float*)d_in[5];
    const float* W2    = (const float*)d_in[6];
    float* out = (float*)d_out;
    float* e_ws = (float*)d_ws;  // NATOMS floats of scratch

    gnn_atom_kernel<<<NATOMS, 256, 0, stream>>>(xyz, zsp, embed, W_rbf, W_msg, W1, W2, e_ws);
    gnn_reduce_kernel<<<1, 256, 0, stream>>>(e_ws, out);
}

// Round 2
// 55.146 us; speedup vs baseline: 2.4139x; 2.4139x over previous
//
#include <hip/hip_runtime.h>
#include <math.h>

#define NATOMS 3000
#define DIM 16
#define NRBF 16
#define CUTOFF 5.0f
#define BOX 45.0f
#define GAMMA 10.0f
#define APB 4          // atoms (waves) per block
#define NBR_CAP 128    // neighbor capacity per atom (mean ~17, huge safety margin)

// One wave per atom: LDS-staged xyz scan -> ordered neighbor compaction ->
// dense RBF/filter/message pass -> in-wave MLP tail.
__global__ __launch_bounds__(256, 3) void gnn_atom_kernel(
    const float* __restrict__ xyz, const int* __restrict__ zsp,
    const float* __restrict__ embed, const float* __restrict__ W_rbf,
    const float* __restrict__ W_msg, const float* __restrict__ W1,
    const float* __restrict__ W2, float* __restrict__ e_out)
{
    __shared__ float sxyz[NATOMS * 3];        // 36000 B
    __shared__ float wrbf[NRBF * DIM];        // 1024 B
    __shared__ int   snbr[APB][NBR_CAP];      // 2048 B
    __shared__ float snr [APB][NBR_CAP];      // 2048 B
    __shared__ float sm  [APB][DIM];
    __shared__ float sh  [APB][DIM];
    __shared__ float st1 [APB][DIM];

    const int tid = threadIdx.x;

    // stage xyz (9000 floats = 2250 float4) and W_rbf
    const float4* x4 = (const float4*)xyz;
    float4* s4 = (float4*)sxyz;
    for (int t = tid; t < (NATOMS * 3) / 4; t += 256) s4[t] = x4[t];
    if (tid < NRBF * DIM) wrbf[tid] = W_rbf[tid];
    __syncthreads();

    const int wave = tid >> 6;
    const int lane = tid & 63;
    const int i = blockIdx.x * APB + wave;    // 750*4 = 3000 exactly

    const float xi = sxyz[3 * i + 0];
    const float yi = sxyz[3 * i + 1];
    const float zi = sxyz[3 * i + 2];

    // --- phase 1: scan + ordered compaction into per-wave LDS list ---
    int cnt = 0;
    for (int jb = 0; jb < NATOMS; jb += 64) {
        const int j = jb + lane;
        bool pred = false;
        float r = 1.0f;
        if (j < NATOMS) {
            float dx = sxyz[3 * j + 0] - xi;
            float dy = sxyz[3 * j + 1] - yi;
            float dz = sxyz[3 * j + 2] - zi;
            dx += ((dx < -0.5f * BOX) ? BOX : 0.0f) - ((dx >= 0.5f * BOX) ? BOX : 0.0f);
            dy += ((dy < -0.5f * BOX) ? BOX : 0.0f) - ((dy >= 0.5f * BOX) ? BOX : 0.0f);
            dz += ((dz < -0.5f * BOX) ? BOX : 0.0f) - ((dz >= 0.5f * BOX) ? BOX : 0.0f);
            const float dsq = dx * dx + dy * dy + dz * dz;
            pred = (dsq < CUTOFF * CUTOFF) && (dsq > 0.0f);
            r = sqrtf(pred ? dsq : 1.0f);
        }
        const unsigned long long mask = __ballot(pred);
        const int prefix = __popcll(mask & ((1ull << lane) - 1ull));
        if (pred) {
            const int slot = cnt + prefix;
            if (slot < NBR_CAP) { snbr[wave][slot] = j; snr[wave][slot] = r; }
        }
        cnt += __popcll(mask);
    }
    if (cnt > NBR_CAP) cnt = NBR_CAP;

    // --- phase 2: dense heavy path over compacted neighbors ---
    float m[DIM];
#pragma unroll
    for (int d = 0; d < DIM; ++d) m[d] = 0.0f;

    for (int l = lane; l < cnt; l += 64) {
        const int j = snbr[wave][l];
        const float r = snr[wave][l];
        float rbf[NRBF];
#pragma unroll
        for (int k = 0; k < NRBF; ++k) {
            const float t = r - (float)k * (CUTOFF / (float)(NRBF - 1));
            rbf[k] = __expf(-GAMMA * t * t);
        }
        const float* hj = embed + (size_t)zsp[j] * DIM;
#pragma unroll
        for (int d = 0; d < DIM; ++d) {
            float f = 0.0f;
#pragma unroll
            for (int k = 0; k < NRBF; ++k) f += rbf[k] * wrbf[k * DIM + d];
            m[d] += f * hj[d];
        }
    }

    // --- phase 3: wave reduction of m[16] ---
#pragma unroll
    for (int d = 0; d < DIM; ++d) {
        float v = m[d];
        for (int off = 32; off >= 1; off >>= 1) v += __shfl_down(v, off, 64);
        if (lane == 0) sm[wave][d] = v;
    }

    // --- phase 4: per-atom MLP tail, wave-internal (lockstep => no barrier) ---
    if (lane < DIM) {
        float acc = 0.0f;
#pragma unroll
        for (int d = 0; d < DIM; ++d) acc += sm[wave][d] * W_msg[d * DIM + lane];
        const float hi = embed[(size_t)zsp[i] * DIM + lane];
        sh[wave][lane] = hi + tanhf(acc);
    }
    if (lane < DIM) {
        float acc = 0.0f;
#pragma unroll
        for (int d = 0; d < DIM; ++d) acc += sh[wave][d] * W1[d * DIM + lane];
        st1[wave][lane] = tanhf(acc);
    }
    if (lane == 0) {
        float e = 0.0f;
#pragma unroll
        for (int d = 0; d < DIM; ++d) e += st1[wave][d] * W2[d];
        e_out[i] = e;
    }
}

// Deterministic final reduction of per-atom energies -> scalar.
__global__ __launch_bounds__(256) void gnn_reduce_kernel(
    const float* __restrict__ e, float* __restrict__ out)
{
    __shared__ float red[4];
    const int tid = threadIdx.x;
    float s = 0.0f;
    for (int i = tid; i < NATOMS; i += 256) s += e[i];
    for (int off = 32; off >= 1; off >>= 1) s += __shfl_down(s, off, 64);
    const int wave = tid >> 6;
    const int lane = tid & 63;
    if (lane == 0) red[wave] = s;
    __syncthreads();
    if (tid == 0) out[0] = red[0] + red[1] + red[2] + red[3];
}

extern "C" void kernel_launch(void* const* d_in, const int* in_sizes, int n_in,
                              void* d_out, int out_size, void* d_ws, size_t ws_size,
                              hipStream_t stream) {
    const float* xyz   = (const float*)d_in[0];
    const int*   zsp   = (const int*)d_in[1];
    const float* embed = (const float*)d_in[2];
    const float* W_rbf = (const float*)d_in[3];
    const float* W_msg = (const float*)d_in[4];
    const float* W1    = (const float*)d_in[5];
    const float* W2    = (const float*)d_in[6];
    float* out = (float*)d_out;
    float* e_ws = (float*)d_ws;  // NATOMS floats of scratch

    gnn_atom_kernel<<<NATOMS / APB, 256, 0, stream>>>(xyz, zsp, embed, W_rbf, W_msg, W1, W2, e_ws);
    gnn_reduce_kernel<<<1, 256, 0, stream>>>(e_ws, out);
}

// Round 3
// 33.568 us; speedup vs baseline: 3.9655x; 1.6428x over previous
//
#include <hip/hip_runtime.h>
#include <math.h>

#define NATOMS 3000
#define DIM 16
#define NRBF 16
#define CUTOFF 5.0f
#define BOX 45.0f
#define GAMMA 10.0f
#define HALF_SPAN 1536           // first wave scans [0,1536), second [1536,3000)
#define NITER (HALF_SPAN / 64)   // 24 iterations per half (uniform trip count)
#define NBR_CAP 64               // per-half capacity (mean ~8.5, max ~30)

// 2 atoms per block; each atom's j-scan split across 2 waves.
// scan (global/L2 reads) -> ordered ballot compaction -> single predicated
// heavy pass -> shuffle reduce -> shuffle-only MLP tail.
__global__ __launch_bounds__(256) void gnn_atom_kernel(
    const float* __restrict__ xyz, const int* __restrict__ zsp,
    const float* __restrict__ embed, const float* __restrict__ W_rbf,
    const float* __restrict__ W_msg, const float* __restrict__ W1,
    const float* __restrict__ W2, float* __restrict__ e_out)
{
    __shared__ float wrbf[NRBF * DIM];     // 1 KB
    __shared__ int   snbr[4][NBR_CAP];     // 1 KB
    __shared__ float snd [4][NBR_CAP];     // 1 KB  (stores dsq)
    __shared__ float sm  [4][DIM];         // partial messages per wave

    const int tid  = threadIdx.x;
    const int w    = tid >> 6;
    const int lane = tid & 63;
    const int alocal = w >> 1;             // 0 or 1
    const int half   = w & 1;              // which j-half this wave scans
    const int i = blockIdx.x * 2 + alocal; // 1500*2 = 3000 exactly

    if (tid < NRBF * DIM) wrbf[tid] = W_rbf[tid];

    const float xi = xyz[3 * i + 0];
    const float yi = xyz[3 * i + 1];
    const float zi = xyz[3 * i + 2];

    // --- phase 1: scan own j-half, ordered compaction into per-wave segment ---
    int cnt = 0;
    const int jbase = half * HALF_SPAN;
#pragma unroll 4
    for (int it = 0; it < NITER; ++it) {
        const int j = jbase + it * 64 + lane;
        bool pred = false;
        float dsq = 0.0f;
        if (j < NATOMS) {
            float dx = xyz[3 * j + 0] - xi;
            float dy = xyz[3 * j + 1] - yi;
            float dz = xyz[3 * j + 2] - zi;
            dx += ((dx < -0.5f * BOX) ? BOX : 0.0f) - ((dx >= 0.5f * BOX) ? BOX : 0.0f);
            dy += ((dy < -0.5f * BOX) ? BOX : 0.0f) - ((dy >= 0.5f * BOX) ? BOX : 0.0f);
            dz += ((dz < -0.5f * BOX) ? BOX : 0.0f) - ((dz >= 0.5f * BOX) ? BOX : 0.0f);
            dsq = fmaf(dx, dx, fmaf(dy, dy, dz * dz));
            pred = (dsq < CUTOFF * CUTOFF) && (dsq > 0.0f);
        }
        const unsigned long long mask = __ballot(pred);
        const int prefix = __popcll(mask & ((1ull << lane) - 1ull));
        if (pred) {
            const int slot = cnt + prefix;
            if (slot < NBR_CAP) { snbr[w][slot] = j; snd[w][slot] = dsq; }
        }
        cnt += __popcll(mask);
    }
    if (cnt > NBR_CAP) cnt = NBR_CAP;
    __syncthreads();   // wrbf staged + compaction lists visible

    // --- phase 2: single predicated heavy pass (<=1 neighbor per lane) ---
    float msg[DIM];
#pragma unroll
    for (int d = 0; d < DIM; ++d) msg[d] = 0.0f;

    if (lane < cnt) {
        const int j = snbr[w][lane];
        const float r = sqrtf(snd[w][lane]);
        float rbf[NRBF];
#pragma unroll
        for (int k = 0; k < NRBF; ++k) {
            const float t = r - (float)k * (CUTOFF / (float)(NRBF - 1));
            rbf[k] = __expf(-GAMMA * t * t);
        }
        const float4* hj4 = (const float4*)(embed + (size_t)zsp[j] * DIM);
        const float4 h0 = hj4[0], h1 = hj4[1], h2 = hj4[2], h3 = hj4[3];
        const float hj[DIM] = {h0.x, h0.y, h0.z, h0.w, h1.x, h1.y, h1.z, h1.w,
                               h2.x, h2.y, h2.z, h2.w, h3.x, h3.y, h3.z, h3.w};
#pragma unroll
        for (int d = 0; d < DIM; ++d) {
            float f = 0.0f;
#pragma unroll
            for (int k = 0; k < NRBF; ++k) f = fmaf(rbf[k], wrbf[k * DIM + d], f);
            msg[d] = f * hj[d];
        }
    }

    // --- phase 3: wave reduce msg[16] -> sm[w] ---
#pragma unroll
    for (int d = 0; d < DIM; ++d) {
        float v = msg[d];
        for (int off = 32; off >= 1; off >>= 1) v += __shfl_down(v, off, 64);
        if (lane == 0) sm[w][d] = v;
    }
    __syncthreads();   // sm visible to tail waves

    // --- phase 4: per-atom MLP tail, waves 0/1, shuffle-only (no barriers) ---
    if (w < 2 && lane < DIM) {
        float macc = 0.0f;
#pragma unroll
        for (int d = 0; d < DIM; ++d) {
            const float md = sm[2 * w][d] + sm[2 * w + 1][d];
            macc = fmaf(md, W_msg[d * DIM + lane], macc);
        }
        const int ia = blockIdx.x * 2 + w;
        const float h = embed[(size_t)zsp[ia] * DIM + lane] + tanhf(macc);
        float a1 = 0.0f;
#pragma unroll
        for (int d = 0; d < DIM; ++d)
            a1 = fmaf(__shfl(h, d, 64), W1[d * DIM + lane], a1);
        float t1 = tanhf(a1) * W2[lane];
#pragma unroll
        for (int off = 8; off >= 1; off >>= 1) t1 += __shfl_xor(t1, off, 64);
        if (lane == 0) e_out[ia] = t1;
    }
}

// Deterministic final reduction of per-atom energies -> scalar.
__global__ __launch_bounds__(256) void gnn_reduce_kernel(
    const float* __restrict__ e, float* __restrict__ out)
{
    __shared__ float red[4];
    const int tid = threadIdx.x;
    float s = 0.0f;
    for (int i = tid; i < NATOMS; i += 256) s += e[i];
    for (int off = 32; off >= 1; off >>= 1) s += __shfl_down(s, off, 64);
    const int wave = tid >> 6;
    const int lane = tid & 63;
    if (lane == 0) red[wave] = s;
    __syncthreads();
    if (tid == 0) out[0] = red[0] + red[1] + red[2] + red[3];
}

extern "C" void kernel_launch(void* const* d_in, const int* in_sizes, int n_in,
                              void* d_out, int out_size, void* d_ws, size_t ws_size,
                              hipStream_t stream) {
    const float* xyz   = (const float*)d_in[0];
    const int*   zsp   = (const int*)d_in[1];
    const float* embed = (const float*)d_in[2];
    const float* W_rbf = (const float*)d_in[3];
    const float* W_msg = (const float*)d_in[4];
    const float* W1    = (const float*)d_in[5];
    const float* W2    = (const float*)d_in[6];
    float* out = (float*)d_out;
    float* e_ws = (float*)d_ws;  // NATOMS floats of scratch

    gnn_atom_kernel<<<NATOMS / 2, 256, 0, stream>>>(xyz, zsp, embed, W_rbf, W_msg, W1, W2, e_ws);
    gnn_reduce_kernel<<<1, 256, 0, stream>>>(e_ws, out);
}

// Round 4
// 33.077 us; speedup vs baseline: 4.0244x; 1.0148x over previous
//
#include <hip/hip_runtime.h>
#include <math.h>

#define NATOMS 3000
#define DIM 16
#define NRBF 16
#define CUTOFF 5.0f
#define C2 (CUTOFF * CUTOFF)
#define BOX 45.0f
#define INV_BOX 0.022222223f   // 1.0f/45.0f
#define GAMMA 10.0f
#define NBR_CAP 64
#define NCHUNK 47              // ceil(3000/64)

// 375 blocks x 4 waves x 2 atoms/wave = 3000 atoms.
// Each wave scans all j for its 2 atoms (shared loads), ordered ballot
// compaction into per-(wave,atom) LDS lists, then one predicated heavy pass
// per atom and a shuffle-only MLP tail on lanes 0-31.
__global__ __launch_bounds__(256) void gnn_atom_kernel(
    const float* __restrict__ xyz, const int* __restrict__ zsp,
    const float* __restrict__ embed, const float* __restrict__ W_rbf,
    const float* __restrict__ W_msg, const float* __restrict__ W1,
    const float* __restrict__ W2, float* __restrict__ e_out)
{
    __shared__ float wrbf[NRBF * DIM];   // 1 KB
    __shared__ int2  spair[8][NBR_CAP];  // 4 KB  (.x = j, .y = dsq bits)
    __shared__ float sm[8][DIM];         // 512 B

    const int tid  = threadIdx.x;
    const int w    = tid >> 6;
    const int lane = tid & 63;
    const int ia   = (blockIdx.x * 4 + w) * 2;   // first atom of this wave

    if (tid < NRBF * DIM) wrbf[tid] = W_rbf[tid];

    const float xa = xyz[3 * ia + 0], ya = xyz[3 * ia + 1], za = xyz[3 * ia + 2];
    const float xb = xyz[3 * ia + 3], yb = xyz[3 * ia + 4], zb = xyz[3 * ia + 5];

    // --- phase 1: shared-load scan + ordered compaction for both atoms ---
    int cntA = 0, cntB = 0;
    const float* p = xyz + 3 * lane;
#pragma unroll 4
    for (int c = 0; c < NCHUNK; ++c) {
        const int j = c * 64 + lane;
        const bool inr = (j < NATOMS);
        float xj = 0.0f, yj = 0.0f, zj = 0.0f;
        if (inr) { xj = p[0]; yj = p[1]; zj = p[2]; }
        p += 192;
        {   // atom A
            float dx = xj - xa, dy = yj - ya, dz = zj - za;
            dx = fmaf(-BOX, rintf(dx * INV_BOX), dx);
            dy = fmaf(-BOX, rintf(dy * INV_BOX), dy);
            dz = fmaf(-BOX, rintf(dz * INV_BOX), dz);
            const float dsq = fmaf(dx, dx, fmaf(dy, dy, dz * dz));
            const bool pred = inr && (dsq < C2) && (dsq > 0.0f);
            const unsigned long long mask = __ballot(pred);
            if (pred) {
                const int slot = cntA + __popcll(mask & ((1ull << lane) - 1ull));
                if (slot < NBR_CAP) spair[w * 2 + 0][slot] = make_int2(j, __float_as_int(dsq));
            }
            cntA += __popcll(mask);
        }
        {   // atom B
            float dx = xj - xb, dy = yj - yb, dz = zj - zb;
            dx = fmaf(-BOX, rintf(dx * INV_BOX), dx);
            dy = fmaf(-BOX, rintf(dy * INV_BOX), dy);
            dz = fmaf(-BOX, rintf(dz * INV_BOX), dz);
            const float dsq = fmaf(dx, dx, fmaf(dy, dy, dz * dz));
            const bool pred = inr && (dsq < C2) && (dsq > 0.0f);
            const unsigned long long mask = __ballot(pred);
            if (pred) {
                const int slot = cntB + __popcll(mask & ((1ull << lane) - 1ull));
                if (slot < NBR_CAP) spair[w * 2 + 1][slot] = make_int2(j, __float_as_int(dsq));
            }
            cntB += __popcll(mask);
        }
    }
    __syncthreads();   // wrbf staged (spair/sm are wave-private)

    // --- phase 2+3: heavy pass + reduce, per atom ---
#pragma unroll
    for (int a = 0; a < 2; ++a) {
        const int cnt = (a == 0) ? cntA : cntB;   // wave-uniform
        float msg[DIM];
#pragma unroll
        for (int d = 0; d < DIM; ++d) msg[d] = 0.0f;
        if (lane < cnt) {
            const int2 pr = spair[w * 2 + a][lane];
            const float r = sqrtf(__int_as_float(pr.y));
            float rbf[NRBF];
#pragma unroll
            for (int k = 0; k < NRBF; ++k) {
                const float t = r - (float)k * (CUTOFF / (float)(NRBF - 1));
                rbf[k] = __expf(-GAMMA * t * t);
            }
            const float4* hj4 = (const float4*)(embed + (size_t)zsp[pr.x] * DIM);
            const float4 h0 = hj4[0], h1 = hj4[1], h2 = hj4[2], h3 = hj4[3];
            const float hj[DIM] = {h0.x, h0.y, h0.z, h0.w, h1.x, h1.y, h1.z, h1.w,
                                   h2.x, h2.y, h2.z, h2.w, h3.x, h3.y, h3.z, h3.w};
#pragma unroll
            for (int d = 0; d < DIM; ++d) {
                float f = 0.0f;
#pragma unroll
                for (int k = 0; k < NRBF; ++k) f = fmaf(rbf[k], wrbf[k * DIM + d], f);
                msg[d] = f * hj[d];
            }
        }
#pragma unroll
        for (int d = 0; d < DIM; ++d) {
            float v = msg[d];
            for (int off = 32; off >= 1; off >>= 1) v += __shfl_down(v, off, 64);
            if (lane == 0) sm[w * 2 + a][d] = v;
        }
    }

    // --- phase 4: MLP tail, both atoms on lanes 0-31 (wave-internal) ---
    if (lane < 32) {
        const int grp  = lane >> 4;          // 0 -> atom ia, 1 -> atom ia+1
        const int col  = lane & 15;
        const int atom = ia + grp;
        float macc = 0.0f;
#pragma unroll
        for (int d = 0; d < DIM; ++d)
            macc = fmaf(sm[w * 2 + grp][d], W_msg[d * DIM + col], macc);
        const float h = embed[(size_t)zsp[atom] * DIM + col] + tanhf(macc);
        float a1 = 0.0f;
#pragma unroll
        for (int d = 0; d < DIM; ++d)
            a1 = fmaf(__shfl(h, (lane & 48) + d, 64), W1[d * DIM + col], a1);
        float t1 = tanhf(a1) * W2[col];
#pragma unroll
        for (int off = 8; off >= 1; off >>= 1) t1 += __shfl_xor(t1, off, 64);
        if (col == 0) e_out[atom] = t1;
    }
}

// Deterministic final reduction of per-atom energies -> scalar.
__global__ __launch_bounds__(256) void gnn_reduce_kernel(
    const float* __restrict__ e, float* __restrict__ out)
{
    __shared__ float red[4];
    const int tid = threadIdx.x;
    float s = 0.0f;
    for (int i = tid; i < NATOMS; i += 256) s += e[i];
    for (int off = 32; off >= 1; off >>= 1) s += __shfl_down(s, off, 64);
    const int wave = tid >> 6;
    const int lane = tid & 63;
    if (lane == 0) red[wave] = s;
    __syncthreads();
    if (tid == 0) out[0] = red[0] + red[1] + red[2] + red[3];
}

extern "C" void kernel_launch(void* const* d_in, const int* in_sizes, int n_in,
                              void* d_out, int out_size, void* d_ws, size_t ws_size,
                              hipStream_t stream) {
    const float* xyz   = (const float*)d_in[0];
    const int*   zsp   = (const int*)d_in[1];
    const float* embed = (const float*)d_in[2];
    const float* W_rbf = (const float*)d_in[3];
    const float* W_msg = (const float*)d_in[4];
    const float* W1    = (const float*)d_in[5];
    const float* W2    = (const float*)d_in[6];
    float* out = (float*)d_out;
    float* e_ws = (float*)d_ws;  // NATOMS floats of scratch

    gnn_atom_kernel<<<NATOMS / 8, 256, 0, stream>>>(xyz, zsp, embed, W_rbf, W_msg, W1, W2, e_ws);
    gnn_reduce_kernel<<<1, 256, 0, stream>>>(e_ws, out);
}

// Round 5
// 28.855 us; speedup vs baseline: 4.6133x; 1.1463x over previous
//
#include <hip/hip_runtime.h>
#include <math.h>

#define NATOMS 3000
#define NPAD   3072            // 12 * 256
#define DIM 16
#define NRBF 16
#define CUTOFF 5.0f
#define C2 (CUTOFF * CUTOFF)
#define BOX 45.0f
#define INV_BOX 0.022222223f   // 1.0f/45.0f
#define GAMMA 10.0f
#define NBR_CAP 64
#define NITER (NPAD / 256)     // 12 float4-chunks of 256 atoms

// ws float layout: sx[0,3072) sy[3072,6144) sz[6144,9216) e[9216,12216)

// Transpose AoS xyz -> padded SoA; pads get +INF so dsq = NaN -> pred false.
__global__ __launch_bounds__(256) void gnn_prep_kernel(
    const float* __restrict__ xyz, float* __restrict__ ws)
{
    const int j = blockIdx.x * 256 + threadIdx.x;   // 12 blocks -> j < 3072
    float x = INFINITY, y = INFINITY, z = INFINITY;
    if (j < NATOMS) { x = xyz[3 * j]; y = xyz[3 * j + 1]; z = xyz[3 * j + 2]; }
    ws[j] = x; ws[NPAD + j] = y; ws[2 * NPAD + j] = z;
}

// 750 blocks x 4 waves; ONE atom per wave (3000 waves total).
// float4 SoA scan -> ordered ballot compaction -> single predicated heavy
// pass -> butterfly reduce -> wave-internal MLP tail. Weights read with
// constant offsets (scalar loads), no LDS staging.
__global__ __launch_bounds__(256) void gnn_atom_kernel(
    const float* __restrict__ xyz, const int* __restrict__ zsp,
    const float* __restrict__ embed, const float* __restrict__ W_rbf,
    const float* __restrict__ W_msg, const float* __restrict__ W1,
    const float* __restrict__ W2, const float* __restrict__ ws,
    float* __restrict__ e_out)
{
    __shared__ int2 spair[4][NBR_CAP];   // 2 KB: .x = j, .y = dsq bits

    const int tid  = threadIdx.x;
    const int w    = tid >> 6;
    const int lane = tid & 63;
    const int i    = blockIdx.x * 4 + w;   // 750*4 = 3000 exactly

    const float xi = xyz[3 * i + 0];
    const float yi = xyz[3 * i + 1];
    const float zi = xyz[3 * i + 2];

    const float4* sx4 = (const float4*)(ws);
    const float4* sy4 = (const float4*)(ws + NPAD);
    const float4* sz4 = (const float4*)(ws + 2 * NPAD);

    // --- phase 1: float4 scan + ordered compaction ---
    int cnt = 0;
#pragma unroll 2
    for (int it = 0; it < NITER; ++it) {
        const int v = it * 64 + lane;
        const float4 x4 = sx4[v];
        const float4 y4 = sy4[v];
        const float4 z4 = sz4[v];
        const float xs[4] = {x4.x, x4.y, x4.z, x4.w};
        const float ys[4] = {y4.x, y4.y, y4.z, y4.w};
        const float zs[4] = {z4.x, z4.y, z4.z, z4.w};
#pragma unroll
        for (int q = 0; q < 4; ++q) {
            float dx = xs[q] - xi, dy = ys[q] - yi, dz = zs[q] - zi;
            dx = fmaf(-BOX, rintf(dx * INV_BOX), dx);
            dy = fmaf(-BOX, rintf(dy * INV_BOX), dy);
            dz = fmaf(-BOX, rintf(dz * INV_BOX), dz);
            const float dsq = fmaf(dx, dx, fmaf(dy, dy, dz * dz));
            const bool pred = (dsq < C2) && (dsq > 0.0f);   // NaN pads fail both
            const unsigned long long mask = __ballot(pred);
            if (pred) {
                const int slot = cnt + __popcll(mask & ((1ull << lane) - 1ull));
                if (slot < NBR_CAP)
                    spair[w][slot] = make_int2(it * 256 + lane * 4 + q,
                                               __float_as_int(dsq));
            }
            cnt += __popcll(mask);
        }
    }
    if (cnt > NBR_CAP) cnt = NBR_CAP;
    __syncthreads();   // cheap safety for cross-lane LDS visibility

    // --- phase 2: single predicated heavy pass (<=1 neighbor per lane) ---
    float msg[DIM];
#pragma unroll
    for (int d = 0; d < DIM; ++d) msg[d] = 0.0f;

    if (lane < cnt) {
        const int2 pr = spair[w][lane];
        const float r = sqrtf(__int_as_float(pr.y));
        float rbf[NRBF];
#pragma unroll
        for (int k = 0; k < NRBF; ++k) {
            const float t = r - (float)k * (CUTOFF / 15.0f);
            rbf[k] = __expf(-GAMMA * t * t);
        }
        const float4* hj4 = (const float4*)(embed + (size_t)zsp[pr.x] * DIM);
        const float4 h0 = hj4[0], h1 = hj4[1], h2 = hj4[2], h3 = hj4[3];
        const float hj[DIM] = {h0.x, h0.y, h0.z, h0.w, h1.x, h1.y, h1.z, h1.w,
                               h2.x, h2.y, h2.z, h2.w, h3.x, h3.y, h3.z, h3.w};
#pragma unroll
        for (int d = 0; d < DIM; ++d) {
            float f = 0.0f;
#pragma unroll
            for (int k = 0; k < NRBF; ++k)
                f = fmaf(rbf[k], W_rbf[k * DIM + d], f);   // constant offsets -> s_load
            msg[d] = f * hj[d];
        }
    }

    // --- phase 3: butterfly reduce; every lane ends with total m[d] ---
#pragma unroll
    for (int d = 0; d < DIM; ++d) {
#pragma unroll
        for (int off = 32; off >= 1; off >>= 1)
            msg[d] += __shfl_xor(msg[d], off, 64);
    }

    // --- phase 4: MLP tail on lanes 0-15 (wave-internal) ---
    if (lane < DIM) {
        float macc = 0.0f;
#pragma unroll
        for (int d = 0; d < DIM; ++d)
            macc = fmaf(msg[d], W_msg[d * DIM + lane], macc);
        const float h = embed[(size_t)zsp[i] * DIM + lane] + tanhf(macc);
        float a1 = 0.0f;
#pragma unroll
        for (int d = 0; d < DIM; ++d)
            a1 = fmaf(__shfl(h, d, 64), W1[d * DIM + lane], a1);
        float t1 = tanhf(a1) * W2[lane];
#pragma unroll
        for (int off = 8; off >= 1; off >>= 1) t1 += __shfl_xor(t1, off, 64);
        if (lane == 0) e_out[i] = t1;
    }
}

// Deterministic final reduction of per-atom energies -> scalar.
__global__ __launch_bounds__(256) void gnn_reduce_kernel(
    const float* __restrict__ e, float* __restrict__ out)
{
    __shared__ float red[4];
    const int tid = threadIdx.x;
    float s = 0.0f;
    for (int i = tid; i < NATOMS; i += 256) s += e[i];
    for (int off = 32; off >= 1; off >>= 1) s += __shfl_down(s, off, 64);
    const int wave = tid >> 6;
    const int lane = tid & 63;
    if (lane == 0) red[wave] = s;
    __syncthreads();
    if (tid == 0) out[0] = red[0] + red[1] + red[2] + red[3];
}

extern "C" void kernel_launch(void* const* d_in, const int* in_sizes, int n_in,
                              void* d_out, int out_size, void* d_ws, size_t ws_size,
                              hipStream_t stream) {
    const float* xyz   = (const float*)d_in[0];
    const int*   zsp   = (const int*)d_in[1];
    const float* embed = (const float*)d_in[2];
    const float* W_rbf = (const float*)d_in[3];
    const float* W_msg = (const float*)d_in[4];
    const float* W1    = (const float*)d_in[5];
    const float* W2    = (const float*)d_in[6];
    float* out = (float*)d_out;

    float* soa = (float*)d_ws;          // 3*NPAD floats
    float* e_ws = soa + 3 * NPAD;       // NATOMS floats

    gnn_prep_kernel<<<NPAD / 256, 256, 0, stream>>>(xyz, soa);
    gnn_atom_kernel<<<NATOMS / 4, 256, 0, stream>>>(xyz, zsp, embed, W_rbf,
                                                    W_msg, W1, W2, soa, e_ws);
    gnn_reduce_kernel<<<1, 256, 0, stream>>>(e_ws, out);
}